// Round 1
// baseline (560.111 us; speedup 1.0000x reference)
//
#include <hip/hip_runtime.h>
#include <math.h>

#define D_EMB 256
#define NHEAD 8
#define HD 32
#define NG 64
#define ATT_SCALE 0.17677669529663687f  // 1/sqrt(32)

// ---------------- meta: starts / counts from sorted batch ----------------
__global__ void k_starts(const int* __restrict__ batch, int n, int* __restrict__ starts) {
    int i = blockIdx.x * blockDim.x + threadIdx.x;
    if (i >= n) return;
    int b = batch[i];
    if (i == 0 || batch[i - 1] != b) starts[b] = i;
}

__global__ void k_counts(const int* __restrict__ starts, int n, int* __restrict__ counts) {
    int g = threadIdx.x;
    if (g < NG) {
        int s = starts[g];
        int e = (g == NG - 1) ? n : starts[g + 1];
        counts[g] = e - s;
    }
}

// ---------------- fp32 GEMM: C = A(MxK) * B(NcolsxK)^T + bias (+resid) ----
#define BM 64
#define BN 64
#define BK 16

__global__ __launch_bounds__(256) void k_gemm_bt(
    const float* __restrict__ A, const float* __restrict__ Bw,
    const float* __restrict__ bias, const float* __restrict__ resid,
    float* __restrict__ Cout, int M, int Ncols, int Kdim) {
    __shared__ float As[BK][BM + 4];
    __shared__ float Bs[BK][BN + 4];

    int tid = threadIdx.x;
    int tm = tid >> 4;        // 0..15
    int tn = tid & 15;        // 0..15
    int row0 = blockIdx.x * BM;
    int col0 = blockIdx.y * BN;

    int lr = tid >> 2;        // 0..63 : tile row to load
    int lk = (tid & 3) * 4;   // 0,4,8,12 : k offset within chunk

    float c[4][4] = {};

    for (int k0 = 0; k0 < Kdim; k0 += BK) {
        // load A tile (guard rows), transposed into As[k][m]
        float4 av = make_float4(0.f, 0.f, 0.f, 0.f);
        int ar = row0 + lr;
        if (ar < M) av = *(const float4*)&A[(size_t)ar * Kdim + k0 + lk];
        As[lk + 0][lr] = av.x; As[lk + 1][lr] = av.y;
        As[lk + 2][lr] = av.z; As[lk + 3][lr] = av.w;
        // load B tile (Ncols is multiple of 64, no guard)
        float4 bv = *(const float4*)&Bw[(size_t)(col0 + lr) * Kdim + k0 + lk];
        Bs[lk + 0][lr] = bv.x; Bs[lk + 1][lr] = bv.y;
        Bs[lk + 2][lr] = bv.z; Bs[lk + 3][lr] = bv.w;
        __syncthreads();

#pragma unroll
        for (int k = 0; k < BK; ++k) {
            float4 a4 = *(const float4*)&As[k][tm * 4];
            float4 b4 = *(const float4*)&Bs[k][tn * 4];
            float a[4] = {a4.x, a4.y, a4.z, a4.w};
            float b[4] = {b4.x, b4.y, b4.z, b4.w};
#pragma unroll
            for (int i = 0; i < 4; ++i)
#pragma unroll
                for (int j = 0; j < 4; ++j)
                    c[i][j] = fmaf(a[i], b[j], c[i][j]);
        }
        __syncthreads();
    }

    int cbase = col0 + tn * 4;
    float4 biasv = *(const float4*)&bias[cbase];
#pragma unroll
    for (int i = 0; i < 4; ++i) {
        int r = row0 + tm * 4 + i;
        if (r >= M) continue;
        float4 o;
        o.x = c[i][0] + biasv.x;
        o.y = c[i][1] + biasv.y;
        o.z = c[i][2] + biasv.z;
        o.w = c[i][3] + biasv.w;
        if (resid) {
            float4 rv = *(const float4*)&resid[(size_t)r * Ncols + cbase];
            o.x += rv.x; o.y += rv.y; o.z += rv.z; o.w += rv.w;
        }
        *(float4*)&Cout[(size_t)r * Ncols + cbase] = o;
    }
}

// ---------------- attention: block = (graph, head, q-chunk of 256) --------
#define TK 64

__global__ __launch_bounds__(256) void k_attn(
    const float* __restrict__ qkv, const int* __restrict__ starts,
    const int* __restrict__ counts, float* __restrict__ ctx) {
    int g = blockIdx.x;
    int h = blockIdx.y;
    int chunk = blockIdx.z;
    int L = counts[g];
    int s0 = starts[g];
    if (chunk * 256 >= L) return;  // uniform across block

    __shared__ float Ks[TK][HD];
    __shared__ float Vs[TK][HD];

    int q = chunk * 256 + threadIdx.x;
    bool active = q < L;

    float qreg[HD];
    if (active) {
        const float4* qp = (const float4*)(qkv + (size_t)(s0 + q) * 768 + h * HD);
#pragma unroll
        for (int d4 = 0; d4 < 8; ++d4) {
            float4 v = qp[d4];
            qreg[d4 * 4 + 0] = v.x; qreg[d4 * 4 + 1] = v.y;
            qreg[d4 * 4 + 2] = v.z; qreg[d4 * 4 + 3] = v.w;
        }
    }

    float m = -INFINITY, l = 0.f;
    float acc[HD];
#pragma unroll
    for (int d = 0; d < HD; ++d) acc[d] = 0.f;

    for (int kt = 0; kt < L; kt += TK) {
        int tkn = min(TK, L - kt);
        // stage K/V tile: tkn rows x 8 float4 each
        for (int idx = threadIdx.x; idx < tkn * 8; idx += 256) {
            int kr = idx >> 3, f = idx & 7;
            const float* src = qkv + (size_t)(s0 + kt + kr) * 768 + 256 + h * HD + f * 4;
            *(float4*)&Ks[kr][f * 4] = *(const float4*)src;
            *(float4*)&Vs[kr][f * 4] = *(const float4*)(src + 256);
        }
        __syncthreads();

        if (active) {
            for (int j = 0; j < tkn; ++j) {
                const float4* kr = (const float4*)Ks[j];
                float s = 0.f;
#pragma unroll
                for (int d4 = 0; d4 < 8; ++d4) {
                    float4 kv = kr[d4];
                    s = fmaf(qreg[d4 * 4 + 0], kv.x, s);
                    s = fmaf(qreg[d4 * 4 + 1], kv.y, s);
                    s = fmaf(qreg[d4 * 4 + 2], kv.z, s);
                    s = fmaf(qreg[d4 * 4 + 3], kv.w, s);
                }
                s *= ATT_SCALE;
                float mnew = fmaxf(m, s);
                float p = __expf(s - mnew);
                if (mnew > m) {
                    float f = __expf(m - mnew);
                    l *= f;
#pragma unroll
                    for (int d = 0; d < HD; ++d) acc[d] *= f;
                    m = mnew;
                }
                l += p;
                const float4* vr = (const float4*)Vs[j];
#pragma unroll
                for (int d4 = 0; d4 < 8; ++d4) {
                    float4 vv = vr[d4];
                    acc[d4 * 4 + 0] = fmaf(p, vv.x, acc[d4 * 4 + 0]);
                    acc[d4 * 4 + 1] = fmaf(p, vv.y, acc[d4 * 4 + 1]);
                    acc[d4 * 4 + 2] = fmaf(p, vv.z, acc[d4 * 4 + 2]);
                    acc[d4 * 4 + 3] = fmaf(p, vv.w, acc[d4 * 4 + 3]);
                }
            }
        }
        __syncthreads();
    }

    if (active) {
        float inv = 1.f / l;
        float4* dst = (float4*)(ctx + (size_t)(s0 + q) * D_EMB + h * HD);
#pragma unroll
        for (int d4 = 0; d4 < 8; ++d4) {
            float4 o;
            o.x = acc[d4 * 4 + 0] * inv;
            o.y = acc[d4 * 4 + 1] * inv;
            o.z = acc[d4 * 4 + 2] * inv;
            o.w = acc[d4 * 4 + 3] * inv;
            dst[d4] = o;
        }
    }
}

// ---------------- per-graph LN stats (graph mode) --------------------------
__global__ __launch_bounds__(256) void k_stats(
    const float* __restrict__ hbuf, const int* __restrict__ starts,
    const int* __restrict__ counts, float* __restrict__ stats) {
    int g = blockIdx.x;
    int s0 = starts[g];
    int cnt = counts[g];
    size_t total4 = (size_t)cnt * (D_EMB / 4);
    const float4* p = (const float4*)(hbuf + (size_t)s0 * D_EMB);

    float sum = 0.f, sq = 0.f;
    for (size_t i = threadIdx.x; i < total4; i += 256) {
        float4 v = p[i];
        sum += v.x + v.y + v.z + v.w;
        sq += v.x * v.x + v.y * v.y + v.z * v.z + v.w * v.w;
    }
#pragma unroll
    for (int o = 32; o > 0; o >>= 1) {
        sum += __shfl_down(sum, o);
        sq += __shfl_down(sq, o);
    }
    __shared__ float ssum[4], ssq[4];
    int wid = threadIdx.x >> 6, lane = threadIdx.x & 63;
    if (lane == 0) { ssum[wid] = sum; ssq[wid] = sq; }
    __syncthreads();
    if (threadIdx.x == 0) {
        float S = 0.f, Q = 0.f;
#pragma unroll
        for (int w = 0; w < 4; ++w) { S += ssum[w]; Q += ssq[w]; }
        float norm = (float)cnt * (float)D_EMB;
        float mean = S / norm;
        float var = Q / norm - mean * mean;
        stats[g * 2] = mean;
        stats[g * 2 + 1] = rsqrtf(var + 1e-5f);
    }
}

// ---------------- LN apply + exact GELU, in place --------------------------
__global__ void k_ln_gelu(float* __restrict__ h, const int* __restrict__ batch,
                          const float* __restrict__ stats, const float* __restrict__ lw,
                          const float* __restrict__ lb, int n) {
    int idx = blockIdx.x * blockDim.x + threadIdx.x;  // float4 index
    if (idx >= n * (D_EMB / 4)) return;
    int row = idx >> 6;
    int c4 = idx & 63;
    int g = batch[row];
    float mean = stats[2 * g], inv = stats[2 * g + 1];
    float4 v = *(float4*)&h[(size_t)idx * 4];
    float4 wv = *(const float4*)&lw[c4 * 4];
    float4 bv = *(const float4*)&lb[c4 * 4];
    float y;
    y = (v.x - mean) * inv * wv.x + bv.x; v.x = 0.5f * y * (1.f + erff(y * 0.70710678118f));
    y = (v.y - mean) * inv * wv.y + bv.y; v.y = 0.5f * y * (1.f + erff(y * 0.70710678118f));
    y = (v.z - mean) * inv * wv.z + bv.z; v.z = 0.5f * y * (1.f + erff(y * 0.70710678118f));
    y = (v.w - mean) * inv * wv.w + bv.w; v.w = 0.5f * y * (1.f + erff(y * 0.70710678118f));
    *(float4*)&h[(size_t)idx * 4] = v;
}

// ---------------- launch ----------------------------------------------------
extern "C" void kernel_launch(void* const* d_in, const int* in_sizes, int n_in,
                              void* d_out, int out_size, void* d_ws, size_t ws_size,
                              hipStream_t stream) {
    const float* x     = (const float*)d_in[0];
    const int*   batch = (const int*)d_in[1];
    const float* in_w  = (const float*)d_in[2];
    const float* in_b  = (const float*)d_in[3];
    const float* out_w = (const float*)d_in[4];
    const float* out_b = (const float*)d_in[5];
    const float* ln_w  = (const float*)d_in[6];
    const float* ln_b  = (const float*)d_in[7];
    int N = in_sizes[1];  // batch vector length
    float* out = (float*)d_out;

    int*   starts = (int*)d_ws;            // 64
    int*   counts = starts + 64;           // 64
    float* stats  = (float*)d_ws + 128;    // 128 (mean, inv_std per graph)
    float* qkv    = (float*)d_ws + 256;    // N*768
    float* ctx    = qkv + (size_t)N * 768; // N*256

    k_starts<<<(N + 255) / 256, 256, 0, stream>>>(batch, N, starts);
    k_counts<<<1, 64, 0, stream>>>(starts, N, counts);

    dim3 g1((N + BM - 1) / BM, 768 / BN);
    k_gemm_bt<<<g1, 256, 0, stream>>>(x, in_w, in_b, nullptr, qkv, N, 768, 256);

    dim3 g2(NG, NHEAD, 2);
    k_attn<<<g2, 256, 0, stream>>>(qkv, starts, counts, ctx);

    dim3 g3((N + BM - 1) / BM, 256 / BN);
    k_gemm_bt<<<g3, 256, 0, stream>>>(ctx, out_w, out_b, x, out, N, 256, 256);

    k_stats<<<NG, 256, 0, stream>>>(out, starts, counts, stats);

    int nv4 = N * (D_EMB / 4);
    k_ln_gelu<<<(nv4 + 255) / 256, 256, 0, stream>>>(out, batch, stats, ln_w, ln_b, N);
}

// Round 2
// 395.900 us; speedup vs baseline: 1.4148x; 1.4148x over previous
//
#include <hip/hip_runtime.h>
#include <math.h>

#define D_EMB 256
#define NHEAD 8
#define HD 32
#define NG 64
#define ATT_SCALE 0.17677669529663687f  // 1/sqrt(32)

typedef __attribute__((ext_vector_type(8))) short short8b;   // 8 bf16 (4 VGPR)
typedef __attribute__((ext_vector_type(4))) float f32x4;

__device__ __forceinline__ unsigned short f2bf(float x) {
    unsigned int u = __builtin_bit_cast(unsigned int, x);
    unsigned int r = (u + 0x7FFFu + ((u >> 16) & 1u)) >> 16;
    return (unsigned short)r;
}

// ---------------- meta: starts / counts from sorted batch ----------------
__global__ void k_starts(const int* __restrict__ batch, int n, int* __restrict__ starts) {
    int i = blockIdx.x * blockDim.x + threadIdx.x;
    if (i >= n) return;
    int b = batch[i];
    if (i == 0 || batch[i - 1] != b) starts[b] = i;
}

__global__ void k_counts(const int* __restrict__ starts, int n, int* __restrict__ counts) {
    int g = threadIdx.x;
    if (g < NG) {
        int s = starts[g];
        int e = (g == NG - 1) ? n : starts[g + 1];
        counts[g] = e - s;
    }
}

// ---------------- fp32 GEMM: C = A(MxK) * B(NcolsxK)^T + bias (+resid) ----
#define BM 64
#define BN 64
#define BK 16

__global__ __launch_bounds__(256) void k_gemm_bt(
    const float* __restrict__ A, const float* __restrict__ Bw,
    const float* __restrict__ bias, const float* __restrict__ resid,
    float* __restrict__ Cout, int M, int Ncols, int Kdim) {
    __shared__ float As[BK][BM + 4];
    __shared__ float Bs[BK][BN + 4];

    int tid = threadIdx.x;
    int tm = tid >> 4;
    int tn = tid & 15;
    int row0 = blockIdx.x * BM;
    int col0 = blockIdx.y * BN;

    int lr = tid >> 2;
    int lk = (tid & 3) * 4;

    float c[4][4] = {};

    for (int k0 = 0; k0 < Kdim; k0 += BK) {
        float4 av = make_float4(0.f, 0.f, 0.f, 0.f);
        int ar = row0 + lr;
        if (ar < M) av = *(const float4*)&A[(size_t)ar * Kdim + k0 + lk];
        As[lk + 0][lr] = av.x; As[lk + 1][lr] = av.y;
        As[lk + 2][lr] = av.z; As[lk + 3][lr] = av.w;
        float4 bv = *(const float4*)&Bw[(size_t)(col0 + lr) * Kdim + k0 + lk];
        Bs[lk + 0][lr] = bv.x; Bs[lk + 1][lr] = bv.y;
        Bs[lk + 2][lr] = bv.z; Bs[lk + 3][lr] = bv.w;
        __syncthreads();

#pragma unroll
        for (int k = 0; k < BK; ++k) {
            float4 a4 = *(const float4*)&As[k][tm * 4];
            float4 b4 = *(const float4*)&Bs[k][tn * 4];
            float a[4] = {a4.x, a4.y, a4.z, a4.w};
            float b[4] = {b4.x, b4.y, b4.z, b4.w};
#pragma unroll
            for (int i = 0; i < 4; ++i)
#pragma unroll
                for (int j = 0; j < 4; ++j)
                    c[i][j] = fmaf(a[i], b[j], c[i][j]);
        }
        __syncthreads();
    }

    int cbase = col0 + tn * 4;
    float4 biasv = *(const float4*)&bias[cbase];
#pragma unroll
    for (int i = 0; i < 4; ++i) {
        int r = row0 + tm * 4 + i;
        if (r >= M) continue;
        float4 o;
        o.x = c[i][0] + biasv.x;
        o.y = c[i][1] + biasv.y;
        o.z = c[i][2] + biasv.z;
        o.w = c[i][3] + biasv.w;
        if (resid) {
            float4 rv = *(const float4*)&resid[(size_t)r * Ncols + cbase];
            o.x += rv.x; o.y += rv.y; o.z += rv.z; o.w += rv.w;
        }
        *(float4*)&Cout[(size_t)r * Ncols + cbase] = o;
    }
}

// ---------------- MFMA attention -------------------------------------------
#define QCHUNK 128
#define KT 32
#define KPAD 56  // bf16 elems per row: 112 B stride (16B aligned)

__global__ __launch_bounds__(256) void k_attn_mfma(
    const float* __restrict__ qkv, const int* __restrict__ starts,
    const int* __restrict__ counts, float* __restrict__ ctx) {
    int g = blockIdx.x, h = blockIdx.y, chunk = blockIdx.z;
    int L = counts[g], s0 = starts[g];
    if (chunk * QCHUNK >= L) return;

    __shared__ __align__(16) unsigned short Klds[KT][KPAD];
    __shared__ __align__(16) unsigned short Vtlds[HD][KPAD];   // [d][key]
    __shared__ __align__(16) unsigned short Plds[4][32][KPAD]; // per-wave [q][k]

    int tid = threadIdx.x;
    int wave = tid >> 6;
    int lane = tid & 63;
    int lrow = lane & 15;
    int lgrp = lane >> 4;

    int qbase = chunk * QCHUNK + wave * 32;

    short8b qfrag[2];
#pragma unroll
    for (int sub = 0; sub < 2; ++sub) {
        int qr = qbase + sub * 16 + lrow;
        if (qr >= L) qr = L - 1;
        const float* qp = qkv + (size_t)(s0 + qr) * 768 + h * HD + lgrp * 8;
        short8b f;
#pragma unroll
        for (int j = 0; j < 8; ++j) f[j] = (short)f2bf(qp[j]);
        qfrag[sub] = f;
    }

    float mrow[8], lsum[8];
#pragma unroll
    for (int i = 0; i < 8; ++i) { mrow[i] = -INFINITY; lsum[i] = 0.f; }
    f32x4 acc[2][2];
#pragma unroll
    for (int a = 0; a < 2; ++a)
#pragma unroll
        for (int b = 0; b < 2; ++b) acc[a][b] = (f32x4){0.f, 0.f, 0.f, 0.f};

    for (int kt = 0; kt < L; kt += KT) {
        {
            int key = tid >> 3;
            int d4 = (tid & 7) * 4;
            int krow = kt + key;
            float4 kv = make_float4(0.f, 0.f, 0.f, 0.f);
            float4 vv = make_float4(0.f, 0.f, 0.f, 0.f);
            if (krow < L) {
                const float* base = qkv + (size_t)(s0 + krow) * 768 + 256 + h * HD + d4;
                kv = *(const float4*)base;
                vv = *(const float4*)(base + 256);
            }
            ushort4 kp;
            kp.x = f2bf(kv.x); kp.y = f2bf(kv.y); kp.z = f2bf(kv.z); kp.w = f2bf(kv.w);
            *(ushort4*)&Klds[key][d4] = kp;
            Vtlds[d4 + 0][key] = f2bf(vv.x);
            Vtlds[d4 + 1][key] = f2bf(vv.y);
            Vtlds[d4 + 2][key] = f2bf(vv.z);
            Vtlds[d4 + 3][key] = f2bf(vv.w);
        }
        __syncthreads();

        short8b kfrag[2];
#pragma unroll
        for (int kn = 0; kn < 2; ++kn)
            kfrag[kn] = *(const short8b*)&Klds[kn * 16 + lrow][lgrp * 8];

        f32x4 s[2][2];
#pragma unroll
        for (int qm = 0; qm < 2; ++qm)
#pragma unroll
            for (int kn = 0; kn < 2; ++kn)
                s[qm][kn] = __builtin_amdgcn_mfma_f32_16x16x32_bf16(
                    qfrag[qm], kfrag[kn], (f32x4){0.f, 0.f, 0.f, 0.f}, 0, 0, 0);

        bool k0ok = (kt + lrow) < L;
        bool k1ok = (kt + 16 + lrow) < L;
#pragma unroll
        for (int qm = 0; qm < 2; ++qm) {
#pragma unroll
            for (int r = 0; r < 4; ++r) {
                int si = qm * 4 + r;
                float sc0 = k0ok ? s[qm][0][r] * ATT_SCALE : -INFINITY;
                float sc1 = k1ok ? s[qm][1][r] * ATT_SCALE : -INFINITY;
                float mx = fmaxf(sc0, sc1);
#pragma unroll
                for (int off = 1; off < 16; off <<= 1)
                    mx = fmaxf(mx, __shfl_xor(mx, off));
                float mnew = fmaxf(mrow[si], mx);
                float p0 = __expf(sc0 - mnew);
                float p1 = __expf(sc1 - mnew);
                float ps = p0 + p1;
#pragma unroll
                for (int off = 1; off < 16; off <<= 1)
                    ps += __shfl_xor(ps, off);
                float f = __expf(mrow[si] - mnew);
                lsum[si] = lsum[si] * f + ps;
                mrow[si] = mnew;
                acc[qm][0][r] *= f;
                acc[qm][1][r] *= f;
                int qq = qm * 16 + lgrp * 4 + r;
                Plds[wave][qq][lrow] = f2bf(p0);
                Plds[wave][qq][16 + lrow] = f2bf(p1);
            }
        }

        asm volatile("s_waitcnt lgkmcnt(0)" ::: "memory");

        short8b pfrag[2];
#pragma unroll
        for (int qm = 0; qm < 2; ++qm)
            pfrag[qm] = *(const short8b*)&Plds[wave][qm * 16 + lrow][lgrp * 8];
#pragma unroll
        for (int dsub = 0; dsub < 2; ++dsub) {
            short8b vfrag = *(const short8b*)&Vtlds[dsub * 16 + lrow][lgrp * 8];
#pragma unroll
            for (int qm = 0; qm < 2; ++qm)
                acc[qm][dsub] = __builtin_amdgcn_mfma_f32_16x16x32_bf16(
                    pfrag[qm], vfrag, acc[qm][dsub], 0, 0, 0);
        }
        __syncthreads();
    }

#pragma unroll
    for (int qm = 0; qm < 2; ++qm) {
#pragma unroll
        for (int r = 0; r < 4; ++r) {
            int q = qbase + qm * 16 + lgrp * 4 + r;
            if (q >= L) continue;
            float inv = 1.f / lsum[qm * 4 + r];
            float* dst = ctx + (size_t)(s0 + q) * D_EMB + h * HD;
            dst[lrow] = acc[qm][0][r] * inv;
            dst[16 + lrow] = acc[qm][1][r] * inv;
        }
    }
}

// ---------------- per-graph LN stats (graph mode) --------------------------
__global__ __launch_bounds__(256) void k_stats(
    const float* __restrict__ hbuf, const int* __restrict__ starts,
    const int* __restrict__ counts, float* __restrict__ stats) {
    int g = blockIdx.x;
    int s0 = starts[g];
    int cnt = counts[g];
    size_t total4 = (size_t)cnt * (D_EMB / 4);
    const float4* p = (const float4*)(hbuf + (size_t)s0 * D_EMB);

    float sum = 0.f, sq = 0.f;
    for (size_t i = threadIdx.x; i < total4; i += 256) {
        float4 v = p[i];
        sum += v.x + v.y + v.z + v.w;
        sq += v.x * v.x + v.y * v.y + v.z * v.z + v.w * v.w;
    }
#pragma unroll
    for (int o = 32; o > 0; o >>= 1) {
        sum += __shfl_down(sum, o);
        sq += __shfl_down(sq, o);
    }
    __shared__ float ssum[4], ssq[4];
    int wid = threadIdx.x >> 6, lane = threadIdx.x & 63;
    if (lane == 0) { ssum[wid] = sum; ssq[wid] = sq; }
    __syncthreads();
    if (threadIdx.x == 0) {
        float S = 0.f, Q = 0.f;
#pragma unroll
        for (int w = 0; w < 4; ++w) { S += ssum[w]; Q += ssq[w]; }
        float norm = (float)cnt * (float)D_EMB;
        float mean = S / norm;
        float var = Q / norm - mean * mean;
        stats[g * 2] = mean;
        stats[g * 2 + 1] = rsqrtf(var + 1e-5f);
    }
}

// ---------------- LN apply + exact GELU, in place --------------------------
__global__ void k_ln_gelu(float* __restrict__ h, const int* __restrict__ batch,
                          const float* __restrict__ stats, const float* __restrict__ lw,
                          const float* __restrict__ lb, int n) {
    int idx = blockIdx.x * blockDim.x + threadIdx.x;
    if (idx >= n * (D_EMB / 4)) return;
    int row = idx >> 6;
    int c4 = idx & 63;
    int g = batch[row];
    float mean = stats[2 * g], inv = stats[2 * g + 1];
    float4 v = *(float4*)&h[(size_t)idx * 4];
    float4 wv = *(const float4*)&lw[c4 * 4];
    float4 bv = *(const float4*)&lb[c4 * 4];
    float y;
    y = (v.x - mean) * inv * wv.x + bv.x; v.x = 0.5f * y * (1.f + erff(y * 0.70710678118f));
    y = (v.y - mean) * inv * wv.y + bv.y; v.y = 0.5f * y * (1.f + erff(y * 0.70710678118f));
    y = (v.z - mean) * inv * wv.z + bv.z; v.z = 0.5f * y * (1.f + erff(y * 0.70710678118f));
    y = (v.w - mean) * inv * wv.w + bv.w; v.w = 0.5f * y * (1.f + erff(y * 0.70710678118f));
    *(float4*)&h[(size_t)idx * 4] = v;
}

// ---------------- launch ----------------------------------------------------
extern "C" void kernel_launch(void* const* d_in, const int* in_sizes, int n_in,
                              void* d_out, int out_size, void* d_ws, size_t ws_size,
                              hipStream_t stream) {
    const float* x     = (const float*)d_in[0];
    const int*   batch = (const int*)d_in[1];
    const float* in_w  = (const float*)d_in[2];
    const float* in_b  = (const float*)d_in[3];
    const float* out_w = (const float*)d_in[4];
    const float* out_b = (const float*)d_in[5];
    const float* ln_w  = (const float*)d_in[6];
    const float* ln_b  = (const float*)d_in[7];
    int N = in_sizes[1];
    float* out = (float*)d_out;

    int*   starts = (int*)d_ws;
    int*   counts = starts + 64;
    float* stats  = (float*)d_ws + 128;
    float* qkv    = (float*)d_ws + 256;
    float* ctx    = qkv + (size_t)N * 768;

    k_starts<<<(N + 255) / 256, 256, 0, stream>>>(batch, N, starts);
    k_counts<<<1, 64, 0, stream>>>(starts, N, counts);

    dim3 g1((N + BM - 1) / BM, 768 / BN);
    k_gemm_bt<<<g1, 256, 0, stream>>>(x, in_w, in_b, nullptr, qkv, N, 768, 256);

    k_attn_mfma<<<dim3(NG, NHEAD, 4), 256, 0, stream>>>(qkv, starts, counts, ctx);

    dim3 g3((N + BM - 1) / BM, 256 / BN);
    k_gemm_bt<<<g3, 256, 0, stream>>>(ctx, out_w, out_b, x, out, N, 256, 256);

    k_stats<<<NG, 256, 0, stream>>>(out, starts, counts, stats);

    int nv4 = N * (D_EMB / 4);
    k_ln_gelu<<<(nv4 + 255) / 256, 256, 0, stream>>>(out, batch, stats, ln_w, ln_b, N);
}

// Round 3
// 211.600 us; speedup vs baseline: 2.6470x; 1.8710x over previous
//
#include <hip/hip_runtime.h>
#include <math.h>

#define D_EMB 256
#define NHEAD 8
#define HD 32
#define NG 64
#define ATT_SCALE 0.17677669529663687f  // 1/sqrt(32)

typedef __attribute__((ext_vector_type(8))) short short8b;   // 8 bf16 (4 VGPR)
typedef __attribute__((ext_vector_type(4))) float f32x4;

__device__ __forceinline__ unsigned short f2bf(float x) {
    unsigned int u = __builtin_bit_cast(unsigned int, x);
    unsigned int r = (u + 0x7FFFu + ((u >> 16) & 1u)) >> 16;
    return (unsigned short)r;
}

__device__ __forceinline__ short8b pack8(float4 a, float4 b) {
    short8b r;
    r[0] = (short)f2bf(a.x); r[1] = (short)f2bf(a.y);
    r[2] = (short)f2bf(a.z); r[3] = (short)f2bf(a.w);
    r[4] = (short)f2bf(b.x); r[5] = (short)f2bf(b.y);
    r[6] = (short)f2bf(b.z); r[7] = (short)f2bf(b.w);
    return r;
}

// ---------------- meta: starts / counts from sorted batch ----------------
__global__ void k_starts(const int* __restrict__ batch, int n, int* __restrict__ starts) {
    int i = blockIdx.x * blockDim.x + threadIdx.x;
    if (i >= n) return;
    int b = batch[i];
    if (i == 0 || batch[i - 1] != b) starts[b] = i;
}

__global__ void k_counts(const int* __restrict__ starts, int n, int* __restrict__ counts) {
    int g = threadIdx.x;
    if (g < NG) {
        int s = starts[g];
        int e = (g == NG - 1) ? n : starts[g + 1];
        counts[g] = e - s;
    }
}

// ---------------- bf16 MFMA GEMM: C = A(MxK) * W(NxK)^T + bias (+resid) ----
// 128x128 tile, 4 waves (2x2), each wave 64x64 (4x4 of 16x16x32 MFMA).
#define LSW 40  // LDS row stride in ushort (32 data + 8 pad = 80 B)

__global__ __launch_bounds__(256) void k_gemm_mfma(
    const float* __restrict__ A, const float* __restrict__ Bw,
    const float* __restrict__ bias, const float* __restrict__ resid,
    float* __restrict__ Cout, int M, int Ncols, int Kdim) {
    __shared__ __align__(16) unsigned short Alds[128][LSW];
    __shared__ __align__(16) unsigned short Blds[128][LSW];

    int tid = threadIdx.x;
    int wave = tid >> 6, lane = tid & 63;
    int lrow = lane & 15, lgrp = lane >> 4;
    int wr = wave >> 1, wc = wave & 1;
    int row0 = blockIdx.x * 128, col0 = blockIdx.y * 128;
    int srow = tid >> 1;             // 0..127
    int sk = (tid & 1) * 16;         // 0 or 16

    f32x4 acc[4][4];
#pragma unroll
    for (int i = 0; i < 4; ++i)
#pragma unroll
        for (int j = 0; j < 4; ++j) acc[i][j] = (f32x4){0.f, 0.f, 0.f, 0.f};

    for (int k0 = 0; k0 < Kdim; k0 += 32) {
        // stage A tile (guarded rows) with fused f32->bf16
        {
            float4 v0 = {0,0,0,0}, v1 = {0,0,0,0}, v2 = {0,0,0,0}, v3 = {0,0,0,0};
            int ar = row0 + srow;
            if (ar < M) {
                const float4* ap = (const float4*)(A + (size_t)ar * Kdim + k0 + sk);
                v0 = ap[0]; v1 = ap[1]; v2 = ap[2]; v3 = ap[3];
            }
            *(short8b*)&Alds[srow][sk] = pack8(v0, v1);
            *(short8b*)&Alds[srow][sk + 8] = pack8(v2, v3);
            // B tile: Ncols is a multiple of 128, no guard
            const float4* bp = (const float4*)(Bw + (size_t)(col0 + srow) * Kdim + k0 + sk);
            float4 w0 = bp[0], w1 = bp[1], w2 = bp[2], w3 = bp[3];
            *(short8b*)&Blds[srow][sk] = pack8(w0, w1);
            *(short8b*)&Blds[srow][sk + 8] = pack8(w2, w3);
        }
        __syncthreads();

        short8b af[4], bf[4];
#pragma unroll
        for (int mi = 0; mi < 4; ++mi)
            af[mi] = *(const short8b*)&Alds[wr * 64 + mi * 16 + lrow][lgrp * 8];
#pragma unroll
        for (int ni = 0; ni < 4; ++ni)
            bf[ni] = *(const short8b*)&Blds[wc * 64 + ni * 16 + lrow][lgrp * 8];
#pragma unroll
        for (int mi = 0; mi < 4; ++mi)
#pragma unroll
            for (int ni = 0; ni < 4; ++ni)
                acc[mi][ni] = __builtin_amdgcn_mfma_f32_16x16x32_bf16(
                    af[mi], bf[ni], acc[mi][ni], 0, 0, 0);
        __syncthreads();
    }

    // epilogue: C row = row0+wr*64+mi*16+lgrp*4+r, col = col0+wc*64+ni*16+lrow
#pragma unroll
    for (int ni = 0; ni < 4; ++ni) {
        int col = col0 + wc * 64 + ni * 16 + lrow;
        float bv = bias[col];
#pragma unroll
        for (int mi = 0; mi < 4; ++mi) {
            int rowb = row0 + wr * 64 + mi * 16 + lgrp * 4;
#pragma unroll
            for (int r = 0; r < 4; ++r) {
                int row = rowb + r;
                if (row < M) {
                    float v = acc[mi][ni][r] + bv;
                    if (resid) v += resid[(size_t)row * Ncols + col];
                    Cout[(size_t)row * Ncols + col] = v;
                }
            }
        }
    }
}

// ---------------- MFMA attention (swapped QK^T, in-register softmax) -------
// block = (graph, head, 128-q chunk); 4 waves x 32 q. K-tiles of 32 keys.
// S^T = mfma(K, Q): lane owns q = lane&15 (per 16-tile), keys in regs.
#define KT 32

__global__ __launch_bounds__(256) void k_attn_mfma(
    const float* __restrict__ qkv, const int* __restrict__ starts,
    const int* __restrict__ counts, float* __restrict__ ctx) {
    int g = blockIdx.x, h = blockIdx.y, chunk = blockIdx.z;
    int L = counts[g], s0 = starts[g];
    if (chunk * 128 >= L) return;

    __shared__ __align__(16) unsigned short Klds[KT][LSW];
    __shared__ __align__(16) unsigned short Vt[HD][LSW];  // [d][sigma(key)]

    int tid = threadIdx.x;
    int wave = tid >> 6, lane = tid & 63;
    int lrow = lane & 15, lgrp = lane >> 4;
    int qbase = chunk * 128 + wave * 32;

    // Q fragments (B-operand: col q = lane&15, k(d) = lgrp*8+j)
    short8b qfrag[2];
#pragma unroll
    for (int qm = 0; qm < 2; ++qm) {
        int qr = qbase + qm * 16 + lrow;
        if (qr >= L) qr = L - 1;  // clamp; output discarded
        const float4* qp = (const float4*)(qkv + (size_t)(s0 + qr) * 768 + h * HD + lgrp * 8);
        qfrag[qm] = pack8(qp[0], qp[1]);
    }

    float mrun[2] = {-INFINITY, -INFINITY};
    float lrun[2] = {0.f, 0.f};
    f32x4 acc[2][2];  // [qm][dsub]: O^T tile, col=q=lane&15, row=d=lgrp*4+r
#pragma unroll
    for (int a = 0; a < 2; ++a)
#pragma unroll
        for (int b = 0; b < 2; ++b) acc[a][b] = (f32x4){0.f, 0.f, 0.f, 0.f};

    for (int kt = 0; kt < L; kt += KT) {
        // stage K row-major and V^T with permuted columns sigma(key)
        {
            int key = tid >> 3;
            int d4 = (tid & 7) * 4;
            float4 kv = {0,0,0,0}, vv = {0,0,0,0};
            if (kt + key < L) {
                const float* base = qkv + (size_t)(s0 + kt + key) * 768 + 256 + h * HD + d4;
                kv = *(const float4*)base;
                vv = *(const float4*)(base + 256);
            }
            ushort4 kp;
            kp.x = f2bf(kv.x); kp.y = f2bf(kv.y); kp.z = f2bf(kv.z); kp.w = f2bf(kv.w);
            *(ushort4*)&Klds[key][d4] = kp;
            int c = ((key >> 2) & 3) * 8 + ((key >> 4) & 1) * 4 + (key & 3);
            Vt[d4 + 0][c] = f2bf(vv.x);
            Vt[d4 + 1][c] = f2bf(vv.y);
            Vt[d4 + 2][c] = f2bf(vv.z);
            Vt[d4 + 3][c] = f2bf(vv.w);
        }
        __syncthreads();

        // K fragments (A-operand: row key = lane&15 per 16-tile)
        short8b kfrag[2];
#pragma unroll
        for (int kn = 0; kn < 2; ++kn)
            kfrag[kn] = *(const short8b*)&Klds[kn * 16 + lrow][lgrp * 8];

        // S^T[key][q]: col=lane&15=q, row=key=kn*16+lgrp*4+r
        f32x4 s[2][2];
#pragma unroll
        for (int kn = 0; kn < 2; ++kn)
#pragma unroll
            for (int qm = 0; qm < 2; ++qm)
                s[kn][qm] = __builtin_amdgcn_mfma_f32_16x16x32_bf16(
                    kfrag[kn], qfrag[qm], (f32x4){0.f, 0.f, 0.f, 0.f}, 0, 0, 0);

        // online softmax: per lane 8 scores per qm; reduce over lgrp via 2 shuffles
        float p[2][2][4];
#pragma unroll
        for (int qm = 0; qm < 2; ++qm) {
            float mx = -INFINITY;
#pragma unroll
            for (int kn = 0; kn < 2; ++kn)
#pragma unroll
                for (int r = 0; r < 4; ++r) {
                    bool ok = (kt + kn * 16 + lgrp * 4 + r) < L;
                    float sc = ok ? s[kn][qm][r] * ATT_SCALE : -INFINITY;
                    p[qm][kn][r] = sc;
                    mx = fmaxf(mx, sc);
                }
            mx = fmaxf(mx, __shfl_xor(mx, 16));
            mx = fmaxf(mx, __shfl_xor(mx, 32));
            float mnew = fmaxf(mrun[qm], mx);
            float fsc = __expf(mrun[qm] - mnew);
            mrun[qm] = mnew;
            float ps = 0.f;
#pragma unroll
            for (int kn = 0; kn < 2; ++kn)
#pragma unroll
                for (int r = 0; r < 4; ++r) {
                    float pv = __expf(p[qm][kn][r] - mnew);
                    p[qm][kn][r] = pv;
                    ps += pv;
                }
            ps += __shfl_xor(ps, 16);
            ps += __shfl_xor(ps, 32);
            lrun[qm] = lrun[qm] * fsc + ps;
#pragma unroll
            for (int dsub = 0; dsub < 2; ++dsub)
#pragma unroll
                for (int r = 0; r < 4; ++r) acc[qm][dsub][r] *= fsc;
        }

        // pack P as B-operand: position j<4 -> key=lgrp*4+j (kn=0), j>=4 -> 16+lgrp*4+(j-4)
        short8b pf[2];
#pragma unroll
        for (int qm = 0; qm < 2; ++qm) {
            short8b t;
            t[0] = (short)f2bf(p[qm][0][0]); t[1] = (short)f2bf(p[qm][0][1]);
            t[2] = (short)f2bf(p[qm][0][2]); t[3] = (short)f2bf(p[qm][0][3]);
            t[4] = (short)f2bf(p[qm][1][0]); t[5] = (short)f2bf(p[qm][1][1]);
            t[6] = (short)f2bf(p[qm][1][2]); t[7] = (short)f2bf(p[qm][1][3]);
            pf[qm] = t;
        }

        // PV: O^T[d][q] += V^T P^T ; V^T staged with matching key permutation
#pragma unroll
        for (int dsub = 0; dsub < 2; ++dsub) {
            short8b vf = *(const short8b*)&Vt[dsub * 16 + lrow][lgrp * 8];
#pragma unroll
            for (int qm = 0; qm < 2; ++qm)
                acc[qm][dsub] = __builtin_amdgcn_mfma_f32_16x16x32_bf16(
                    vf, pf[qm], acc[qm][dsub], 0, 0, 0);
        }
        __syncthreads();
    }

    // epilogue: q = qbase+qm*16+lane&15, d = dsub*16+lgrp*4+r
#pragma unroll
    for (int qm = 0; qm < 2; ++qm) {
        int q = qbase + qm * 16 + lrow;
        if (q >= L) continue;
        float inv = 1.f / lrun[qm];
        float* dst = ctx + (size_t)(s0 + q) * D_EMB + h * HD;
#pragma unroll
        for (int dsub = 0; dsub < 2; ++dsub)
#pragma unroll
            for (int r = 0; r < 4; ++r)
                dst[dsub * 16 + lgrp * 4 + r] = acc[qm][dsub][r] * inv;
    }
}

// ---------------- per-graph LN stats (graph mode) --------------------------
__global__ __launch_bounds__(256) void k_stats(
    const float* __restrict__ hbuf, const int* __restrict__ starts,
    const int* __restrict__ counts, float* __restrict__ stats) {
    int g = blockIdx.x;
    int s0 = starts[g];
    int cnt = counts[g];
    size_t total4 = (size_t)cnt * (D_EMB / 4);
    const float4* p = (const float4*)(hbuf + (size_t)s0 * D_EMB);

    float sum = 0.f, sq = 0.f;
    for (size_t i = threadIdx.x; i < total4; i += 256) {
        float4 v = p[i];
        sum += v.x + v.y + v.z + v.w;
        sq += v.x * v.x + v.y * v.y + v.z * v.z + v.w * v.w;
    }
#pragma unroll
    for (int o = 32; o > 0; o >>= 1) {
        sum += __shfl_down(sum, o);
        sq += __shfl_down(sq, o);
    }
    __shared__ float ssum[4], ssq[4];
    int wid = threadIdx.x >> 6, lane = threadIdx.x & 63;
    if (lane == 0) { ssum[wid] = sum; ssq[wid] = sq; }
    __syncthreads();
    if (threadIdx.x == 0) {
        float S = 0.f, Q = 0.f;
#pragma unroll
        for (int w = 0; w < 4; ++w) { S += ssum[w]; Q += ssq[w]; }
        float norm = (float)cnt * (float)D_EMB;
        float mean = S / norm;
        float var = Q / norm - mean * mean;
        stats[g * 2] = mean;
        stats[g * 2 + 1] = rsqrtf(var + 1e-5f);
    }
}

// ---------------- LN apply + exact GELU, in place --------------------------
__global__ void k_ln_gelu(float* __restrict__ h, const int* __restrict__ batch,
                          const float* __restrict__ stats, const float* __restrict__ lw,
                          const float* __restrict__ lb, int n) {
    int idx = blockIdx.x * blockDim.x + threadIdx.x;
    if (idx >= n * (D_EMB / 4)) return;
    int row = idx >> 6;
    int c4 = idx & 63;
    int g = batch[row];
    float mean = stats[2 * g], inv = stats[2 * g + 1];
    float4 v = *(float4*)&h[(size_t)idx * 4];
    float4 wv = *(const float4*)&lw[c4 * 4];
    float4 bv = *(const float4*)&lb[c4 * 4];
    float y;
    y = (v.x - mean) * inv * wv.x + bv.x; v.x = 0.5f * y * (1.f + erff(y * 0.70710678118f));
    y = (v.y - mean) * inv * wv.y + bv.y; v.y = 0.5f * y * (1.f + erff(y * 0.70710678118f));
    y = (v.z - mean) * inv * wv.z + bv.z; v.z = 0.5f * y * (1.f + erff(y * 0.70710678118f));
    y = (v.w - mean) * inv * wv.w + bv.w; v.w = 0.5f * y * (1.f + erff(y * 0.70710678118f));
    *(float4*)&h[(size_t)idx * 4] = v;
}

// ---------------- launch ----------------------------------------------------
extern "C" void kernel_launch(void* const* d_in, const int* in_sizes, int n_in,
                              void* d_out, int out_size, void* d_ws, size_t ws_size,
                              hipStream_t stream) {
    const float* x     = (const float*)d_in[0];
    const int*   batch = (const int*)d_in[1];
    const float* in_w  = (const float*)d_in[2];
    const float* in_b  = (const float*)d_in[3];
    const float* out_w = (const float*)d_in[4];
    const float* out_b = (const float*)d_in[5];
    const float* ln_w  = (const float*)d_in[6];
    const float* ln_b  = (const float*)d_in[7];
    int N = in_sizes[1];
    float* out = (float*)d_out;

    int*   starts = (int*)d_ws;
    int*   counts = starts + 64;
    float* stats  = (float*)d_ws + 128;
    float* qkv    = (float*)d_ws + 256;
    float* ctx    = qkv + (size_t)N * 768;

    k_starts<<<(N + 255) / 256, 256, 0, stream>>>(batch, N, starts);
    k_counts<<<1, 64, 0, stream>>>(starts, N, counts);

    dim3 g1((N + 127) / 128, 768 / 128);
    k_gemm_mfma<<<g1, 256, 0, stream>>>(x, in_w, in_b, nullptr, qkv, N, 768, 256);

    k_attn_mfma<<<dim3(NG, NHEAD, 4), 256, 0, stream>>>(qkv, starts, counts, ctx);

    dim3 g3((N + 127) / 128, 256 / 128);
    k_gemm_mfma<<<g3, 256, 0, stream>>>(ctx, out_w, out_b, x, out, N, 256, 256);

    k_stats<<<NG, 256, 0, stream>>>(out, starts, counts, stats);

    int nv4 = N * (D_EMB / 4);
    k_ln_gelu<<<(nv4 + 255) / 256, 256, 0, stream>>>(out, batch, stats, ln_w, ln_b, N);
}